// Round 15
// baseline (1080.719 us; speedup 1.0000x reference)
//
#include <hip/hip_runtime.h>
#include <cstdint>
#include <cstddef>

namespace {
constexpr int kL = 16;                    // levels
constexpr uint32_t kT = 1u << 19;         // hash table entries per level
constexpr uint32_t kTmask = kT - 1u;
constexpr uint32_t kP1 = 2654435761u;     // spatial hash primes
constexpr uint32_t kP2 = 805459861u;

constexpr int kRES[16] = {16, 20, 25, 32, 40, 50, 64, 80,
                          101, 128, 161, 203, 256, 322, 406, 512};

// level modes
constexpr int MODE_HASH = 0;   // random hash gather (levels 8-15)
constexpr int MODE_DENSE1 = 1; // dense grid, 4B entries (level 7)
constexpr int MODE_DENSE2 = 2; // dense grid, z-paired 8B entries (levels 0-6)
}

__device__ __forceinline__ uint32_t hash3(uint32_t c0, uint32_t c1, uint32_t c2) {
    return (c0 ^ (c1 * kP1) ^ (c2 * kP2)) & kTmask;
}

__device__ __forceinline__ uint32_t f32_to_bf16_rne(float f) {
    const uint32_t u = __float_as_uint(f);
    return (u + 0x7fffu + ((u >> 16) & 1u)) >> 16;
}

// unpack packed bf16x2: low half = feature0, high = feature1
__device__ __forceinline__ float bfx(uint32_t u) { return __uint_as_float(u << 16); }
__device__ __forceinline__ float bfy(uint32_t u) { return __uint_as_float(u & 0xffff0000u); }

// ---------------------------------------------------------------------------
// Pre-pass 1: hashmap [L,T,F] f32 -> packed 2xbf16 per entry (4B).
// ---------------------------------------------------------------------------
__global__ __launch_bounds__(256) void convert_tables(
    const float4* __restrict__ hm4, uint2* __restrict__ tbl_bf, int npairs)
{
    const int i = blockIdx.x * 256 + threadIdx.x;
    if (i >= npairs) return;
    const float4 v = hm4[i];
    uint2 o;
    o.x = (f32_to_bf16_rne(v.y) << 16) | f32_to_bf16_rne(v.x);
    o.y = (f32_to_bf16_rne(v.w) << 16) | f32_to_bf16_rne(v.z);
    tbl_bf[i] = o;
}

// ---------------------------------------------------------------------------
// Pre-pass 2a: dense z-paired table for one coarse level (collision
// semantics preserved exactly: we copy hashed VALUES per corner).
// ---------------------------------------------------------------------------
template <int R, int LVL>
__global__ __launch_bounds__(256) void build_dense2(
    const uint32_t* __restrict__ tbl_bf, uint2* __restrict__ d2)
{
    const int n = (R + 1) * (R + 1) * R;
    const int s = blockIdx.x * 256 + threadIdx.x;
    if (s >= n) return;
    const int c2 = s % R;
    const int t = s / R;
    const int c1 = t % (R + 1);
    const int c0 = t / (R + 1);
    const uint32_t* tbl = tbl_bf + (size_t)LVL * (size_t)kT;
    uint2 o;
    o.x = tbl[hash3((uint32_t)c0, (uint32_t)c1, (uint32_t)c2)];
    o.y = tbl[hash3((uint32_t)c0, (uint32_t)c1, (uint32_t)(c2 + 1))];
    d2[s] = o;
}

// Pre-pass 2b: dense 4B table (level 7).
template <int R, int LVL>
__global__ __launch_bounds__(256) void build_dense1(
    const uint32_t* __restrict__ tbl_bf, uint32_t* __restrict__ d1)
{
    const int n = (R + 1) * (R + 1) * (R + 1);
    const int s = blockIdx.x * 256 + threadIdx.x;
    if (s >= n) return;
    const int c2 = s % (R + 1);
    const int t = s / (R + 1);
    const int c1 = t % (R + 1);
    const int c0 = t / (R + 1);
    const uint32_t* tbl = tbl_bf + (size_t)LVL * (size_t)kT;
    d1[s] = tbl[hash3((uint32_t)c0, (uint32_t)c1, (uint32_t)c2)];
}

// ---------------------------------------------------------------------------
struct Params16 {
    int mode[16];
    int res[16];
    float fres[16];
    unsigned long long off[16];   // byte offset of this level's table in ws
};

// ---------------------------------------------------------------------------
// MEGA pass with COARSE/FINE CO-SCHEDULING. 8 phases; phase j interleaves
// blocks of fine level 8+j (even blocks) with coarse level j (odd blocks).
// Rationale (r14 post-mortem): fine hash levels are bound by per-CU miss
// handling (MSHR/L2-tag) with waves mostly *waiting*; coarse dense levels
// are L1-hit/TA-bound and barely use MSHRs. Level-major ran these two
// regimes in SERIES; interleaving runs coarse work inside fine-miss
// latency -> max() instead of sum. Per-phase L2 footprint: 2MB fine table
// + <=2.2MB coarse table ~ 4MB per-XCD L2 (worst pairs 4.1-4.2MB).
// 4 points/thread (32 outstanding gathers/wave), unchanged from r14.
// ---------------------------------------------------------------------------
__global__ __launch_bounds__(256, 4) void hashgrid_levels(
    const float* __restrict__ x,         // [P,3]
    const char* __restrict__ wsbase,     // ws base (tables live here)
    uint32_t* __restrict__ wsb,          // [kL][P] packed bf16x2 results
    int P, int blocksPerLevel, Params16 prm)
{
    // phase pairing: even r -> fine level 8+phase, odd r -> coarse level phase
    const int phase = blockIdx.x / (2 * blocksPerLevel);
    const int r = blockIdx.x - phase * (2 * blocksPerLevel);
    const int l = (r & 1) ? phase : (8 + phase);
    const int b = r >> 1;

    const int t = b * 256 + threadIdx.x;
    const int p0 = 4 * t;
    if (p0 >= P) return;

    const int mode = prm.mode[l];
    const int R = prm.res[l];
    const float fres = prm.fres[l];
    const char* tblb = wsbase + prm.off[l];

    // load 4 points (3x float4, 16B-aligned since p0*12B % 16 == 0)
    float px[4], py[4], pz[4];
    if (p0 + 3 < P) {
        const float4* __restrict__ xp4 =
            reinterpret_cast<const float4*>(x + (size_t)p0 * 3);
        const float4 v0 = xp4[0], v1 = xp4[1], v2 = xp4[2];
        px[0] = v0.x; py[0] = v0.y; pz[0] = v0.z;
        px[1] = v0.w; py[1] = v1.x; pz[1] = v1.y;
        px[2] = v1.z; py[2] = v1.w; pz[2] = v2.x;
        px[3] = v2.y; py[3] = v2.z; pz[3] = v2.w;
    } else {
#pragma unroll
        for (int q = 0; q < 4; ++q) {
            const int pc = (p0 + q < P) ? (p0 + q) : (P - 1);
            px[q] = x[(size_t)pc * 3 + 0];
            py[q] = x[(size_t)pc * 3 + 1];
            pz[q] = x[(size_t)pc * 3 + 2];
        }
    }

    // geometry (fp32 ops match the reference exactly)
    int i0[4], i1[4], i2[4];
    float fx[4], fy[4], fz[4];
#pragma unroll
    for (int q = 0; q < 4; ++q) {
        const float xs0 = px[q] * fres, xs1 = py[q] * fres, xs2 = pz[q] * fres;
        const float fl0 = floorf(xs0), fl1 = floorf(xs1), fl2 = floorf(xs2);
        fx[q] = xs0 - fl0; fy[q] = xs1 - fl1; fz[q] = xs2 - fl2;
        i0[q] = (int)fl0; i1[q] = (int)fl1; i2[q] = (int)fl2;
    }

    float r0[4], r1[4];

    if (mode == MODE_DENSE2) {
        const uint2* __restrict__ d2 = reinterpret_cast<const uint2*>(tblb);
        const int sB = R, sA = R * (R + 1);
        // all 16 8B gathers issued as one clause
        uint2 u[4][4];
#pragma unroll
        for (int q = 0; q < 4; ++q) {
            const int base = (i0[q] * (R + 1) + i1[q]) * R + i2[q];
            u[q][0] = d2[base];
            u[q][1] = d2[base + sB];
            u[q][2] = d2[base + sA];
            u[q][3] = d2[base + sA + sB];
        }
#pragma unroll
        for (int q = 0; q < 4; ++q) {
            const float wx0 = 1.0f - fx[q], wx1 = fx[q];
            const float wy0 = 1.0f - fy[q], wy1 = fy[q];
            const float wz0 = 1.0f - fz[q], wz1 = fz[q];
            const float w00 = wx0 * wy0, w01 = wx0 * wy1;
            const float w10 = wx1 * wy0, w11 = wx1 * wy1;
            float a0 = 0.0f, a1 = 0.0f;
            a0 = fmaf(w00 * wz0, bfx(u[q][0].x), a0); a1 = fmaf(w00 * wz0, bfy(u[q][0].x), a1);
            a0 = fmaf(w00 * wz1, bfx(u[q][0].y), a0); a1 = fmaf(w00 * wz1, bfy(u[q][0].y), a1);
            a0 = fmaf(w01 * wz0, bfx(u[q][1].x), a0); a1 = fmaf(w01 * wz0, bfy(u[q][1].x), a1);
            a0 = fmaf(w01 * wz1, bfx(u[q][1].y), a0); a1 = fmaf(w01 * wz1, bfy(u[q][1].y), a1);
            a0 = fmaf(w10 * wz0, bfx(u[q][2].x), a0); a1 = fmaf(w10 * wz0, bfy(u[q][2].x), a1);
            a0 = fmaf(w10 * wz1, bfx(u[q][2].y), a0); a1 = fmaf(w10 * wz1, bfy(u[q][2].y), a1);
            a0 = fmaf(w11 * wz0, bfx(u[q][3].x), a0); a1 = fmaf(w11 * wz0, bfy(u[q][3].x), a1);
            a0 = fmaf(w11 * wz1, bfx(u[q][3].y), a0); a1 = fmaf(w11 * wz1, bfy(u[q][3].y), a1);
            r0[q] = a0; r1[q] = a1;
        }
    } else {
        const uint32_t* __restrict__ tbl = reinterpret_cast<const uint32_t*>(tblb);
        uint32_t idx[4][8];
        if (mode == MODE_DENSE1) {
            const int sB = R + 1, sA = (R + 1) * (R + 1);
#pragma unroll
            for (int q = 0; q < 4; ++q) {
                const int base = (i0[q] * (R + 1) + i1[q]) * (R + 1) + i2[q];
                idx[q][0] = base;           idx[q][1] = base + 1;
                idx[q][2] = base + sB;      idx[q][3] = base + sB + 1;
                idx[q][4] = base + sA;      idx[q][5] = base + sA + 1;
                idx[q][6] = base + sA + sB; idx[q][7] = base + sA + sB + 1;
            }
        } else {
#pragma unroll
            for (int q = 0; q < 4; ++q) {
                const uint32_t h0a = (uint32_t)i0[q], h0b = h0a + 1u;
                const uint32_t h1a = (uint32_t)i1[q] * kP1, h1b = h1a + kP1;
                const uint32_t h2a = (uint32_t)i2[q] * kP2, h2b = h2a + kP2;
                idx[q][0] = (h0a ^ h1a ^ h2a) & kTmask;
                idx[q][1] = (h0a ^ h1a ^ h2b) & kTmask;
                idx[q][2] = (h0a ^ h1b ^ h2a) & kTmask;
                idx[q][3] = (h0a ^ h1b ^ h2b) & kTmask;
                idx[q][4] = (h0b ^ h1a ^ h2a) & kTmask;
                idx[q][5] = (h0b ^ h1a ^ h2b) & kTmask;
                idx[q][6] = (h0b ^ h1b ^ h2a) & kTmask;
                idx[q][7] = (h0b ^ h1b ^ h2b) & kTmask;
            }
        }
        // all 32 4B gathers issued as one clause
        uint32_t u[4][8];
#pragma unroll
        for (int q = 0; q < 4; ++q) {
#pragma unroll
            for (int c = 0; c < 8; ++c) u[q][c] = tbl[idx[q][c]];
        }
#pragma unroll
        for (int q = 0; q < 4; ++q) {
            const float wx0 = 1.0f - fx[q], wx1 = fx[q];
            const float wy0 = 1.0f - fy[q], wy1 = fy[q];
            const float wz0 = 1.0f - fz[q], wz1 = fz[q];
            float w[8];
            w[0] = wx0 * wy0 * wz0; w[1] = wx0 * wy0 * wz1;
            w[2] = wx0 * wy1 * wz0; w[3] = wx0 * wy1 * wz1;
            w[4] = wx1 * wy0 * wz0; w[5] = wx1 * wy0 * wz1;
            w[6] = wx1 * wy1 * wz0; w[7] = wx1 * wy1 * wz1;
            float a0 = 0.0f, a1 = 0.0f;
#pragma unroll
            for (int c = 0; c < 8; ++c) {
                a0 = fmaf(w[c], bfx(u[q][c]), a0);
                a1 = fmaf(w[c], bfy(u[q][c]), a1);
            }
            r0[q] = a0; r1[q] = a1;
        }
    }

    uint32_t pk[4];
#pragma unroll
    for (int q = 0; q < 4; ++q)
        pk[q] = (f32_to_bf16_rne(r1[q]) << 16) | f32_to_bf16_rne(r0[q]);

    uint32_t* dst = wsb + (size_t)l * (size_t)P + (size_t)p0;
    if (p0 + 3 < P) {
        *reinterpret_cast<uint4*>(dst) = make_uint4(pk[0], pk[1], pk[2], pk[3]);
    } else {
#pragma unroll
        for (int q = 0; q < 4; ++q)
            if (p0 + q < P) dst[q] = pk[q];
    }
}

// ---------------------------------------------------------------------------
// wsb[l][p] bf16x2 -> out[p][32] f32, LDS-staged, both sides coalesced.
// ---------------------------------------------------------------------------
__global__ __launch_bounds__(256) void hashgrid_transpose(
    const uint32_t* __restrict__ wsb, float4* __restrict__ out4, int P)
{
    __shared__ uint32_t lds[256 * 17];
    const int tid = threadIdx.x;
    const int base = blockIdx.x * 256;

#pragma unroll
    for (int l = 0; l < kL; ++l) {
        const int p = base + tid;
        const uint32_t v = (p < P) ? wsb[(size_t)l * (size_t)P + (size_t)p] : 0u;
        lds[tid * 17 + l] = v;
    }
    __syncthreads();

    const int nvec = min(P - base, 256) * 8;
#pragma unroll
    for (int j = 0; j < 8; ++j) {
        const int tvec = j * 256 + tid;
        if (tvec < nvec) {
            const int pl = tvec >> 3;
            const int m = tvec & 7;
            const uint32_t ua = lds[pl * 17 + 2 * m];
            const uint32_t ub = lds[pl * 17 + 2 * m + 1];
            out4[(size_t)base * 8 + (size_t)tvec] =
                make_float4(bfx(ua), bfy(ua), bfx(ub), bfy(ub));
        }
    }
}

// ---------------------------------------------------------------------------
// Fallback (monolithic fp32): only if ws too small.
// ---------------------------------------------------------------------------
__global__ __launch_bounds__(256) void hashgrid_fwd_mono(
    const float* __restrict__ x, const float* __restrict__ hashmap,
    float4* __restrict__ out4, int P)
{
    const int p = blockIdx.x * 256 + threadIdx.x;
    if (p >= P) return;
    const float px = x[p * 3 + 0], py = x[p * 3 + 1], pz = x[p * 3 + 2];
    float acc[32];
#pragma unroll
    for (int l = 0; l < kL; ++l) {
        const float fres = (float)kRES[l];
        const float xs0 = px * fres, xs1 = py * fres, xs2 = pz * fres;
        const float fl0 = floorf(xs0), fl1 = floorf(xs1), fl2 = floorf(xs2);
        const float fx = xs0 - fl0, fy = xs1 - fl1, fz = xs2 - fl2;
        const uint32_t i0 = (uint32_t)(int)fl0, i1 = (uint32_t)(int)fl1, i2 = (uint32_t)(int)fl2;
        const uint32_t h0a = i0, h0b = i0 + 1u;
        const uint32_t h1a = i1 * kP1, h1b = (i1 + 1u) * kP1;
        const uint32_t h2a = i2 * kP2, h2b = (i2 + 1u) * kP2;
        uint32_t idx[8];
        idx[0] = (h0a ^ h1a ^ h2a) & kTmask; idx[1] = (h0a ^ h1a ^ h2b) & kTmask;
        idx[2] = (h0a ^ h1b ^ h2a) & kTmask; idx[3] = (h0a ^ h1b ^ h2b) & kTmask;
        idx[4] = (h0b ^ h1a ^ h2a) & kTmask; idx[5] = (h0b ^ h1a ^ h2b) & kTmask;
        idx[6] = (h0b ^ h1b ^ h2a) & kTmask; idx[7] = (h0b ^ h1b ^ h2b) & kTmask;
        const float2* tbl = reinterpret_cast<const float2*>(hashmap) + (size_t)l * kT;
        float2 f[8];
#pragma unroll
        for (int c = 0; c < 8; ++c) f[c] = tbl[idx[c]];
        const float wx0 = 1.0f - fx, wx1 = fx;
        const float wy0 = 1.0f - fy, wy1 = fy;
        const float wz0 = 1.0f - fz, wz1 = fz;
        float w[8];
        w[0] = wx0 * wy0 * wz0; w[1] = wx0 * wy0 * wz1;
        w[2] = wx0 * wy1 * wz0; w[3] = wx0 * wy1 * wz1;
        w[4] = wx1 * wy0 * wz0; w[5] = wx1 * wy0 * wz1;
        w[6] = wx1 * wy1 * wz0; w[7] = wx1 * wy1 * wz1;
        float a0 = 0.0f, a1 = 0.0f;
#pragma unroll
        for (int c = 0; c < 8; ++c) {
            a0 = fmaf(w[c], f[c].x, a0);
            a1 = fmaf(w[c], f[c].y, a1);
        }
        acc[2 * l + 0] = a0; acc[2 * l + 1] = a1;
    }
    float4* dst = out4 + (size_t)p * 8;
#pragma unroll
    for (int j = 0; j < 8; ++j)
        dst[j] = make_float4(acc[4 * j], acc[4 * j + 1], acc[4 * j + 2], acc[4 * j + 3]);
}

extern "C" void kernel_launch(void* const* d_in, const int* in_sizes, int n_in,
                              void* d_out, int out_size, void* d_ws, size_t ws_size,
                              hipStream_t stream) {
    const float* x = (const float*)d_in[0];
    const float* hashmap = (const float*)d_in[1];
    float4* out4 = (float4*)d_out;

    const int P = in_sizes[0] / 3;
    const int block = 256;
    const int grid_p = (P + block - 1) / block;

    // ws layout: [0,32MB) bf16 hash tables | dense tables (~7MB) | wsb results
    const size_t tbl_bytes = (size_t)kL * (size_t)kT * 4u;               // 32 MB
    size_t dense_off[8];
    size_t cur = tbl_bytes;
    for (int l = 0; l < 8; ++l) {
        const size_t R = (size_t)kRES[l];
        const size_t bytes = (l < 7) ? (R + 1) * (R + 1) * R * 8
                                     : (R + 1) * (R + 1) * (R + 1) * 4;
        cur = (cur + 255) & ~(size_t)255;
        dense_off[l] = cur;
        cur += bytes;
    }
    cur = (cur + 255) & ~(size_t)255;
    const size_t wsb_off = cur;
    const size_t need = wsb_off + (size_t)kL * (size_t)P * 4u;
    if (ws_size < need) {
        hashgrid_fwd_mono<<<grid_p, block, 0, stream>>>(x, hashmap, out4, P);
        return;
    }

    char* wsc = (char*)d_ws;
    uint32_t* tbl_bf = (uint32_t*)wsc;
    uint32_t* wsb = (uint32_t*)(wsc + wsb_off);

    // pass 1: bf16-pack the hash tables
    const int npairs = (int)((size_t)kL * (size_t)kT / 2);
    convert_tables<<<(npairs + block - 1) / block, block, 0, stream>>>(
        (const float4*)hashmap, (uint2*)tbl_bf, npairs);

    // pass 2: build dense tables for levels 0-7
#define BUILD2(R, L) build_dense2<R, L><<<(((R+1)*(R+1)*R) + 255) / 256, 256, 0, stream>>>( \
        tbl_bf, (uint2*)(wsc + dense_off[L]))
    BUILD2(16, 0); BUILD2(20, 1); BUILD2(25, 2); BUILD2(32, 3);
    BUILD2(40, 4); BUILD2(50, 5); BUILD2(64, 6);
#undef BUILD2
    build_dense1<80, 7><<<((81 * 81 * 81) + 255) / 256, 256, 0, stream>>>(
        tbl_bf, (uint32_t*)(wsc + dense_off[7]));

    // pass 3: mega gather with coarse/fine co-scheduled phases
    Params16 prm;
    for (int l = 0; l < kL; ++l) {
        prm.res[l] = kRES[l];
        prm.fres[l] = (float)kRES[l];
        if (l < 7)       { prm.mode[l] = MODE_DENSE2; prm.off[l] = dense_off[l]; }
        else if (l == 7) { prm.mode[l] = MODE_DENSE1; prm.off[l] = dense_off[l]; }
        else             { prm.mode[l] = MODE_HASH;
                           prm.off[l] = (size_t)l * (size_t)kT * 4u; }
    }
    const int blocksPerLevel = ((P + 3) / 4 + block - 1) / block;
    hashgrid_levels<<<kL * blocksPerLevel, block, 0, stream>>>(
        x, wsc, wsb, P, blocksPerLevel, prm);

    // pass 4: transpose to [P,32]
    hashgrid_transpose<<<grid_p, block, 0, stream>>>(wsb, out4, P);
}

// Round 16
// 789.971 us; speedup vs baseline: 1.3680x; 1.3680x over previous
//
#include <hip/hip_runtime.h>
#include <cstdint>
#include <cstddef>

namespace {
constexpr int kL = 16;                    // levels
constexpr uint32_t kT = 1u << 19;         // hash table entries per level
constexpr uint32_t kTmask = kT - 1u;
constexpr uint32_t kP1 = 2654435761u;     // spatial hash primes
constexpr uint32_t kP2 = 805459861u;

constexpr int kRES[16] = {16, 20, 25, 32, 40, 50, 64, 80,
                          101, 128, 161, 203, 256, 322, 406, 512};

// level modes
constexpr int MODE_HASH = 0;   // random hash gather, 8x4B   (levels 8-15)
constexpr int MODE_DENSE1 = 1; // dense grid, 8x4B           (level 7)
constexpr int MODE_DENSE2 = 2; // dense z-pair, 4x8B         (level 6)
constexpr int MODE_YZ = 3;     // dense yz-face quad, 2x16B  (level 5)
constexpr int MODE_OCT = 4;    // dense full octant, 2x16B   (levels 0-4)
}

__device__ __forceinline__ uint32_t hash3(uint32_t c0, uint32_t c1, uint32_t c2) {
    return (c0 ^ (c1 * kP1) ^ (c2 * kP2)) & kTmask;
}

__device__ __forceinline__ uint32_t f32_to_bf16_rne(float f) {
    const uint32_t u = __float_as_uint(f);
    return (u + 0x7fffu + ((u >> 16) & 1u)) >> 16;
}

// unpack packed bf16x2: low half = feature0, high = feature1
__device__ __forceinline__ float bfx(uint32_t u) { return __uint_as_float(u << 16); }
__device__ __forceinline__ float bfy(uint32_t u) { return __uint_as_float(u & 0xffff0000u); }

// ---------------------------------------------------------------------------
// Pre-pass 1: hashmap [L,T,F] f32 -> packed 2xbf16 per entry (4B).
// ---------------------------------------------------------------------------
__global__ __launch_bounds__(256) void convert_tables(
    const float4* __restrict__ hm4, uint2* __restrict__ tbl_bf, int npairs)
{
    const int i = blockIdx.x * 256 + threadIdx.x;
    if (i >= npairs) return;
    const float4 v = hm4[i];
    uint2 o;
    o.x = (f32_to_bf16_rne(v.y) << 16) | f32_to_bf16_rne(v.x);
    o.y = (f32_to_bf16_rne(v.w) << 16) | f32_to_bf16_rne(v.z);
    tbl_bf[i] = o;
}

// ---------------------------------------------------------------------------
// Pre-pass 2: widened dense tables (collision semantics preserved exactly:
// we copy hashed VALUES per corner; overlapping slots duplicate values).
// ---------------------------------------------------------------------------
// Octant: slot (c0,c1,c2), c* in [0,R-1], holds all 8 corners (32B).
// Corner order = CORNER_OFFS (dz fastest): lo = c000,c001,c010,c011;
// hi = c100,c101,c110,c111.
template <int R, int LVL>
__global__ __launch_bounds__(256) void build_oct(
    const uint32_t* __restrict__ tbl_bf, uint4* __restrict__ oc)
{
    const int n = R * R * R;
    const int s = blockIdx.x * 256 + threadIdx.x;
    if (s >= n) return;
    const int c2 = s % R;
    const int t = s / R;
    const int c1 = t % R;
    const int c0 = t / R;
    const uint32_t* tbl = tbl_bf + (size_t)LVL * (size_t)kT;
    const uint32_t h0a = (uint32_t)c0, h0b = h0a + 1u;
    const uint32_t h1a = (uint32_t)c1 * kP1, h1b = h1a + kP1;
    const uint32_t h2a = (uint32_t)c2 * kP2, h2b = h2a + kP2;
    uint4 lo, hi;
    lo.x = tbl[(h0a ^ h1a ^ h2a) & kTmask];
    lo.y = tbl[(h0a ^ h1a ^ h2b) & kTmask];
    lo.z = tbl[(h0a ^ h1b ^ h2a) & kTmask];
    lo.w = tbl[(h0a ^ h1b ^ h2b) & kTmask];
    hi.x = tbl[(h0b ^ h1a ^ h2a) & kTmask];
    hi.y = tbl[(h0b ^ h1a ^ h2b) & kTmask];
    hi.z = tbl[(h0b ^ h1b ^ h2a) & kTmask];
    hi.w = tbl[(h0b ^ h1b ^ h2b) & kTmask];
    oc[2 * s + 0] = lo;
    oc[2 * s + 1] = hi;
}

// yz-face quad: slot (c0,c1,c2), c0 in [0,R], c1,c2 in [0,R-1]; holds the
// 4 corners (c0, c1+dy, c2+dz), dz fastest (16B).
template <int R, int LVL>
__global__ __launch_bounds__(256) void build_yz(
    const uint32_t* __restrict__ tbl_bf, uint4* __restrict__ fc)
{
    const int n = (R + 1) * R * R;
    const int s = blockIdx.x * 256 + threadIdx.x;
    if (s >= n) return;
    const int c2 = s % R;
    const int t = s / R;
    const int c1 = t % R;
    const int c0 = t / R;
    const uint32_t* tbl = tbl_bf + (size_t)LVL * (size_t)kT;
    const uint32_t h0 = (uint32_t)c0;
    const uint32_t h1a = (uint32_t)c1 * kP1, h1b = h1a + kP1;
    const uint32_t h2a = (uint32_t)c2 * kP2, h2b = h2a + kP2;
    uint4 f;
    f.x = tbl[(h0 ^ h1a ^ h2a) & kTmask];
    f.y = tbl[(h0 ^ h1a ^ h2b) & kTmask];
    f.z = tbl[(h0 ^ h1b ^ h2a) & kTmask];
    f.w = tbl[(h0 ^ h1b ^ h2b) & kTmask];
    fc[s] = f;
}

// z-pair: slot (c0,c1,c2), c0,c1 in [0,R], c2 in [0,R-1]; 8B.
template <int R, int LVL>
__global__ __launch_bounds__(256) void build_dense2(
    const uint32_t* __restrict__ tbl_bf, uint2* __restrict__ d2)
{
    const int n = (R + 1) * (R + 1) * R;
    const int s = blockIdx.x * 256 + threadIdx.x;
    if (s >= n) return;
    const int c2 = s % R;
    const int t = s / R;
    const int c1 = t % (R + 1);
    const int c0 = t / (R + 1);
    const uint32_t* tbl = tbl_bf + (size_t)LVL * (size_t)kT;
    uint2 o;
    o.x = tbl[hash3((uint32_t)c0, (uint32_t)c1, (uint32_t)c2)];
    o.y = tbl[hash3((uint32_t)c0, (uint32_t)c1, (uint32_t)(c2 + 1))];
    d2[s] = o;
}

// plain dense 4B (level 7).
template <int R, int LVL>
__global__ __launch_bounds__(256) void build_dense1(
    const uint32_t* __restrict__ tbl_bf, uint32_t* __restrict__ d1)
{
    const int n = (R + 1) * (R + 1) * (R + 1);
    const int s = blockIdx.x * 256 + threadIdx.x;
    if (s >= n) return;
    const int c2 = s % (R + 1);
    const int t = s / (R + 1);
    const int c1 = t % (R + 1);
    const int c0 = t / (R + 1);
    const uint32_t* tbl = tbl_bf + (size_t)LVL * (size_t)kT;
    d1[s] = tbl[hash3((uint32_t)c0, (uint32_t)c1, (uint32_t)c2)];
}

// ---------------------------------------------------------------------------
struct Params16 {
    int mode[16];
    int res[16];
    float fres[16];
    unsigned long long off[16];   // byte offset of this level's table in ws
};

// ---------------------------------------------------------------------------
// MEGA level-major pass (r15 co-scheduling REVERTED — it thrashed L1/L2).
// 4 points/thread. Request counts per point: OCT/YZ=2, DENSE2=4,
// DENSE1/HASH=8. Empirical ceiling: ~0.45 gather-lines/cy/CU across
// r12/r13/r14 — time tracks total request count.
// ---------------------------------------------------------------------------
__global__ __launch_bounds__(256, 4) void hashgrid_levels(
    const float* __restrict__ x,         // [P,3]
    const char* __restrict__ wsbase,     // ws base (tables live here)
    uint32_t* __restrict__ wsb,          // [kL][P] packed bf16x2 results
    int P, int blocksPerLevel, Params16 prm)
{
    const int l = blockIdx.x / blocksPerLevel;            // wave-uniform
    const int b = blockIdx.x - l * blocksPerLevel;
    const int t = b * 256 + threadIdx.x;
    const int p0 = 4 * t;
    if (p0 >= P) return;

    const int mode = prm.mode[l];
    const int R = prm.res[l];
    const float fres = prm.fres[l];
    const char* tblb = wsbase + prm.off[l];

    // load 4 points (3x float4, 16B-aligned since p0*12B % 16 == 0)
    float px[4], py[4], pz[4];
    if (p0 + 3 < P) {
        const float4* __restrict__ xp4 =
            reinterpret_cast<const float4*>(x + (size_t)p0 * 3);
        const float4 v0 = xp4[0], v1 = xp4[1], v2 = xp4[2];
        px[0] = v0.x; py[0] = v0.y; pz[0] = v0.z;
        px[1] = v0.w; py[1] = v1.x; pz[1] = v1.y;
        px[2] = v1.z; py[2] = v1.w; pz[2] = v2.x;
        px[3] = v2.y; py[3] = v2.z; pz[3] = v2.w;
    } else {
#pragma unroll
        for (int q = 0; q < 4; ++q) {
            const int pc = (p0 + q < P) ? (p0 + q) : (P - 1);
            px[q] = x[(size_t)pc * 3 + 0];
            py[q] = x[(size_t)pc * 3 + 1];
            pz[q] = x[(size_t)pc * 3 + 2];
        }
    }

    // geometry (fp32 ops match the reference exactly)
    int i0[4], i1[4], i2[4];
    float fx[4], fy[4], fz[4];
#pragma unroll
    for (int q = 0; q < 4; ++q) {
        const float xs0 = px[q] * fres, xs1 = py[q] * fres, xs2 = pz[q] * fres;
        const float fl0 = floorf(xs0), fl1 = floorf(xs1), fl2 = floorf(xs2);
        fx[q] = xs0 - fl0; fy[q] = xs1 - fl1; fz[q] = xs2 - fl2;
        i0[q] = (int)fl0; i1[q] = (int)fl1; i2[q] = (int)fl2;
    }

    float r0[4], r1[4];

    if (mode == MODE_OCT) {
        // slot (x,y,z) -> 8 corners in 32B: 2x uint4, same 32B chunk
        const uint4* __restrict__ oc = reinterpret_cast<const uint4*>(tblb);
        uint4 lo[4], hi[4];
#pragma unroll
        for (int q = 0; q < 4; ++q) {
            const int s = (i0[q] * R + i1[q]) * R + i2[q];
            lo[q] = oc[2 * s + 0];
            hi[q] = oc[2 * s + 1];
        }
#pragma unroll
        for (int q = 0; q < 4; ++q) {
            const float wx0 = 1.0f - fx[q], wx1 = fx[q];
            const float wy0 = 1.0f - fy[q], wy1 = fy[q];
            const float wz0 = 1.0f - fz[q], wz1 = fz[q];
            float w[8];
            w[0] = wx0 * wy0 * wz0; w[1] = wx0 * wy0 * wz1;
            w[2] = wx0 * wy1 * wz0; w[3] = wx0 * wy1 * wz1;
            w[4] = wx1 * wy0 * wz0; w[5] = wx1 * wy0 * wz1;
            w[6] = wx1 * wy1 * wz0; w[7] = wx1 * wy1 * wz1;
            float a0 = 0.0f, a1 = 0.0f;
            a0 = fmaf(w[0], bfx(lo[q].x), a0); a1 = fmaf(w[0], bfy(lo[q].x), a1);
            a0 = fmaf(w[1], bfx(lo[q].y), a0); a1 = fmaf(w[1], bfy(lo[q].y), a1);
            a0 = fmaf(w[2], bfx(lo[q].z), a0); a1 = fmaf(w[2], bfy(lo[q].z), a1);
            a0 = fmaf(w[3], bfx(lo[q].w), a0); a1 = fmaf(w[3], bfy(lo[q].w), a1);
            a0 = fmaf(w[4], bfx(hi[q].x), a0); a1 = fmaf(w[4], bfy(hi[q].x), a1);
            a0 = fmaf(w[5], bfx(hi[q].y), a0); a1 = fmaf(w[5], bfy(hi[q].y), a1);
            a0 = fmaf(w[6], bfx(hi[q].z), a0); a1 = fmaf(w[6], bfy(hi[q].z), a1);
            a0 = fmaf(w[7], bfx(hi[q].w), a0); a1 = fmaf(w[7], bfy(hi[q].w), a1);
            r0[q] = a0; r1[q] = a1;
        }
    } else if (mode == MODE_YZ) {
        // slot (x,y,z) -> 4 corners (x, y+dy, z+dz) in 16B; read x and x+1
        const uint4* __restrict__ fc = reinterpret_cast<const uint4*>(tblb);
        const int sX = R * R;
        uint4 f0[4], f1[4];
#pragma unroll
        for (int q = 0; q < 4; ++q) {
            const int s = (i0[q] * R + i1[q]) * R + i2[q];
            f0[q] = fc[s];
            f1[q] = fc[s + sX];
        }
#pragma unroll
        for (int q = 0; q < 4; ++q) {
            const float wx0 = 1.0f - fx[q], wx1 = fx[q];
            const float wy0 = 1.0f - fy[q], wy1 = fy[q];
            const float wz0 = 1.0f - fz[q], wz1 = fz[q];
            float w[8];
            w[0] = wx0 * wy0 * wz0; w[1] = wx0 * wy0 * wz1;
            w[2] = wx0 * wy1 * wz0; w[3] = wx0 * wy1 * wz1;
            w[4] = wx1 * wy0 * wz0; w[5] = wx1 * wy0 * wz1;
            w[6] = wx1 * wy1 * wz0; w[7] = wx1 * wy1 * wz1;
            float a0 = 0.0f, a1 = 0.0f;
            a0 = fmaf(w[0], bfx(f0[q].x), a0); a1 = fmaf(w[0], bfy(f0[q].x), a1);
            a0 = fmaf(w[1], bfx(f0[q].y), a0); a1 = fmaf(w[1], bfy(f0[q].y), a1);
            a0 = fmaf(w[2], bfx(f0[q].z), a0); a1 = fmaf(w[2], bfy(f0[q].z), a1);
            a0 = fmaf(w[3], bfx(f0[q].w), a0); a1 = fmaf(w[3], bfy(f0[q].w), a1);
            a0 = fmaf(w[4], bfx(f1[q].x), a0); a1 = fmaf(w[4], bfy(f1[q].x), a1);
            a0 = fmaf(w[5], bfx(f1[q].y), a0); a1 = fmaf(w[5], bfy(f1[q].y), a1);
            a0 = fmaf(w[6], bfx(f1[q].z), a0); a1 = fmaf(w[6], bfy(f1[q].z), a1);
            a0 = fmaf(w[7], bfx(f1[q].w), a0); a1 = fmaf(w[7], bfy(f1[q].w), a1);
            r0[q] = a0; r1[q] = a1;
        }
    } else if (mode == MODE_DENSE2) {
        const uint2* __restrict__ d2 = reinterpret_cast<const uint2*>(tblb);
        const int sB = R, sA = R * (R + 1);
        uint2 u[4][4];
#pragma unroll
        for (int q = 0; q < 4; ++q) {
            const int base = (i0[q] * (R + 1) + i1[q]) * R + i2[q];
            u[q][0] = d2[base];
            u[q][1] = d2[base + sB];
            u[q][2] = d2[base + sA];
            u[q][3] = d2[base + sA + sB];
        }
#pragma unroll
        for (int q = 0; q < 4; ++q) {
            const float wx0 = 1.0f - fx[q], wx1 = fx[q];
            const float wy0 = 1.0f - fy[q], wy1 = fy[q];
            const float wz0 = 1.0f - fz[q], wz1 = fz[q];
            const float w00 = wx0 * wy0, w01 = wx0 * wy1;
            const float w10 = wx1 * wy0, w11 = wx1 * wy1;
            float a0 = 0.0f, a1 = 0.0f;
            a0 = fmaf(w00 * wz0, bfx(u[q][0].x), a0); a1 = fmaf(w00 * wz0, bfy(u[q][0].x), a1);
            a0 = fmaf(w00 * wz1, bfx(u[q][0].y), a0); a1 = fmaf(w00 * wz1, bfy(u[q][0].y), a1);
            a0 = fmaf(w01 * wz0, bfx(u[q][1].x), a0); a1 = fmaf(w01 * wz0, bfy(u[q][1].x), a1);
            a0 = fmaf(w01 * wz1, bfx(u[q][1].y), a0); a1 = fmaf(w01 * wz1, bfy(u[q][1].y), a1);
            a0 = fmaf(w10 * wz0, bfx(u[q][2].x), a0); a1 = fmaf(w10 * wz0, bfy(u[q][2].x), a1);
            a0 = fmaf(w10 * wz1, bfx(u[q][2].y), a0); a1 = fmaf(w10 * wz1, bfy(u[q][2].y), a1);
            a0 = fmaf(w11 * wz0, bfx(u[q][3].x), a0); a1 = fmaf(w11 * wz0, bfy(u[q][3].x), a1);
            a0 = fmaf(w11 * wz1, bfx(u[q][3].y), a0); a1 = fmaf(w11 * wz1, bfy(u[q][3].y), a1);
            r0[q] = a0; r1[q] = a1;
        }
    } else {
        // MODE_DENSE1 / MODE_HASH: 8x 4B gathers per point
        const uint32_t* __restrict__ tbl = reinterpret_cast<const uint32_t*>(tblb);
        uint32_t idx[4][8];
        if (mode == MODE_DENSE1) {
            const int sB = R + 1, sA = (R + 1) * (R + 1);
#pragma unroll
            for (int q = 0; q < 4; ++q) {
                const int base = (i0[q] * (R + 1) + i1[q]) * (R + 1) + i2[q];
                idx[q][0] = base;           idx[q][1] = base + 1;
                idx[q][2] = base + sB;      idx[q][3] = base + sB + 1;
                idx[q][4] = base + sA;      idx[q][5] = base + sA + 1;
                idx[q][6] = base + sA + sB; idx[q][7] = base + sA + sB + 1;
            }
        } else {
#pragma unroll
            for (int q = 0; q < 4; ++q) {
                const uint32_t h0a = (uint32_t)i0[q], h0b = h0a + 1u;
                const uint32_t h1a = (uint32_t)i1[q] * kP1, h1b = h1a + kP1;
                const uint32_t h2a = (uint32_t)i2[q] * kP2, h2b = h2a + kP2;
                idx[q][0] = (h0a ^ h1a ^ h2a) & kTmask;
                idx[q][1] = (h0a ^ h1a ^ h2b) & kTmask;
                idx[q][2] = (h0a ^ h1b ^ h2a) & kTmask;
                idx[q][3] = (h0a ^ h1b ^ h2b) & kTmask;
                idx[q][4] = (h0b ^ h1a ^ h2a) & kTmask;
                idx[q][5] = (h0b ^ h1a ^ h2b) & kTmask;
                idx[q][6] = (h0b ^ h1b ^ h2a) & kTmask;
                idx[q][7] = (h0b ^ h1b ^ h2b) & kTmask;
            }
        }
        uint32_t u[4][8];
#pragma unroll
        for (int q = 0; q < 4; ++q) {
#pragma unroll
            for (int c = 0; c < 8; ++c) u[q][c] = tbl[idx[q][c]];
        }
#pragma unroll
        for (int q = 0; q < 4; ++q) {
            const float wx0 = 1.0f - fx[q], wx1 = fx[q];
            const float wy0 = 1.0f - fy[q], wy1 = fy[q];
            const float wz0 = 1.0f - fz[q], wz1 = fz[q];
            float w[8];
            w[0] = wx0 * wy0 * wz0; w[1] = wx0 * wy0 * wz1;
            w[2] = wx0 * wy1 * wz0; w[3] = wx0 * wy1 * wz1;
            w[4] = wx1 * wy0 * wz0; w[5] = wx1 * wy0 * wz1;
            w[6] = wx1 * wy1 * wz0; w[7] = wx1 * wy1 * wz1;
            float a0 = 0.0f, a1 = 0.0f;
#pragma unroll
            for (int c = 0; c < 8; ++c) {
                a0 = fmaf(w[c], bfx(u[q][c]), a0);
                a1 = fmaf(w[c], bfy(u[q][c]), a1);
            }
            r0[q] = a0; r1[q] = a1;
        }
    }

    uint32_t pk[4];
#pragma unroll
    for (int q = 0; q < 4; ++q)
        pk[q] = (f32_to_bf16_rne(r1[q]) << 16) | f32_to_bf16_rne(r0[q]);

    uint32_t* dst = wsb + (size_t)l * (size_t)P + (size_t)p0;
    if (p0 + 3 < P) {
        *reinterpret_cast<uint4*>(dst) = make_uint4(pk[0], pk[1], pk[2], pk[3]);
    } else {
#pragma unroll
        for (int q = 0; q < 4; ++q)
            if (p0 + q < P) dst[q] = pk[q];
    }
}

// ---------------------------------------------------------------------------
// wsb[l][p] bf16x2 -> out[p][32] f32, LDS-staged, both sides coalesced.
// ---------------------------------------------------------------------------
__global__ __launch_bounds__(256) void hashgrid_transpose(
    const uint32_t* __restrict__ wsb, float4* __restrict__ out4, int P)
{
    __shared__ uint32_t lds[256 * 17];
    const int tid = threadIdx.x;
    const int base = blockIdx.x * 256;

#pragma unroll
    for (int l = 0; l < kL; ++l) {
        const int p = base + tid;
        const uint32_t v = (p < P) ? wsb[(size_t)l * (size_t)P + (size_t)p] : 0u;
        lds[tid * 17 + l] = v;
    }
    __syncthreads();

    const int nvec = min(P - base, 256) * 8;
#pragma unroll
    for (int j = 0; j < 8; ++j) {
        const int tvec = j * 256 + tid;
        if (tvec < nvec) {
            const int pl = tvec >> 3;
            const int m = tvec & 7;
            const uint32_t ua = lds[pl * 17 + 2 * m];
            const uint32_t ub = lds[pl * 17 + 2 * m + 1];
            out4[(size_t)base * 8 + (size_t)tvec] =
                make_float4(bfx(ua), bfy(ua), bfx(ub), bfy(ub));
        }
    }
}

// ---------------------------------------------------------------------------
// Fallback (monolithic fp32): only if ws too small.
// ---------------------------------------------------------------------------
__global__ __launch_bounds__(256) void hashgrid_fwd_mono(
    const float* __restrict__ x, const float* __restrict__ hashmap,
    float4* __restrict__ out4, int P)
{
    const int p = blockIdx.x * 256 + threadIdx.x;
    if (p >= P) return;
    const float px = x[p * 3 + 0], py = x[p * 3 + 1], pz = x[p * 3 + 2];
    float acc[32];
#pragma unroll
    for (int l = 0; l < kL; ++l) {
        const float fres = (float)kRES[l];
        const float xs0 = px * fres, xs1 = py * fres, xs2 = pz * fres;
        const float fl0 = floorf(xs0), fl1 = floorf(xs1), fl2 = floorf(xs2);
        const float fx = xs0 - fl0, fy = xs1 - fl1, fz = xs2 - fl2;
        const uint32_t i0 = (uint32_t)(int)fl0, i1 = (uint32_t)(int)fl1, i2 = (uint32_t)(int)fl2;
        const uint32_t h0a = i0, h0b = i0 + 1u;
        const uint32_t h1a = i1 * kP1, h1b = (i1 + 1u) * kP1;
        const uint32_t h2a = i2 * kP2, h2b = (i2 + 1u) * kP2;
        uint32_t idx[8];
        idx[0] = (h0a ^ h1a ^ h2a) & kTmask; idx[1] = (h0a ^ h1a ^ h2b) & kTmask;
        idx[2] = (h0a ^ h1b ^ h2a) & kTmask; idx[3] = (h0a ^ h1b ^ h2b) & kTmask;
        idx[4] = (h0b ^ h1a ^ h2a) & kTmask; idx[5] = (h0b ^ h1a ^ h2b) & kTmask;
        idx[6] = (h0b ^ h1b ^ h2a) & kTmask; idx[7] = (h0b ^ h1b ^ h2b) & kTmask;
        const float2* tbl = reinterpret_cast<const float2*>(hashmap) + (size_t)l * kT;
        float2 f[8];
#pragma unroll
        for (int c = 0; c < 8; ++c) f[c] = tbl[idx[c]];
        const float wx0 = 1.0f - fx, wx1 = fx;
        const float wy0 = 1.0f - fy, wy1 = fy;
        const float wz0 = 1.0f - fz, wz1 = fz;
        float w[8];
        w[0] = wx0 * wy0 * wz0; w[1] = wx0 * wy0 * wz1;
        w[2] = wx0 * wy1 * wz0; w[3] = wx0 * wy1 * wz1;
        w[4] = wx1 * wy0 * wz0; w[5] = wx1 * wy0 * wz1;
        w[6] = wx1 * wy1 * wz0; w[7] = wx1 * wy1 * wz1;
        float a0 = 0.0f, a1 = 0.0f;
#pragma unroll
        for (int c = 0; c < 8; ++c) {
            a0 = fmaf(w[c], f[c].x, a0);
            a1 = fmaf(w[c], f[c].y, a1);
        }
        acc[2 * l + 0] = a0; acc[2 * l + 1] = a1;
    }
    float4* dst = out4 + (size_t)p * 8;
#pragma unroll
    for (int j = 0; j < 8; ++j)
        dst[j] = make_float4(acc[4 * j], acc[4 * j + 1], acc[4 * j + 2], acc[4 * j + 3]);
}

extern "C" void kernel_launch(void* const* d_in, const int* in_sizes, int n_in,
                              void* d_out, int out_size, void* d_ws, size_t ws_size,
                              hipStream_t stream) {
    const float* x = (const float*)d_in[0];
    const float* hashmap = (const float*)d_in[1];
    float4* out4 = (float4*)d_out;

    const int P = in_sizes[0] / 3;
    const int block = 256;
    const int grid_p = (P + block - 1) / block;

    // ws layout: [0,32MB) bf16 hash tables | widened dense tables | wsb
    const size_t tbl_bytes = (size_t)kL * (size_t)kT * 4u;               // 32 MB
    size_t dense_off[8];
    size_t cur = tbl_bytes;
    for (int l = 0; l < 8; ++l) {
        const size_t R = (size_t)kRES[l];
        size_t bytes;
        if (l < 5)       bytes = R * R * R * 32;                 // octant
        else if (l == 5) bytes = (R + 1) * R * R * 16;           // yz-face
        else if (l == 6) bytes = (R + 1) * (R + 1) * R * 8;      // z-pair
        else             bytes = (R + 1) * (R + 1) * (R + 1) * 4; // dense1
        cur = (cur + 255) & ~(size_t)255;
        dense_off[l] = cur;
        cur += bytes;
    }
    cur = (cur + 255) & ~(size_t)255;
    const size_t wsb_off = cur;
    const size_t need = wsb_off + (size_t)kL * (size_t)P * 4u;
    if (ws_size < need) {
        hashgrid_fwd_mono<<<grid_p, block, 0, stream>>>(x, hashmap, out4, P);
        return;
    }

    char* wsc = (char*)d_ws;
    uint32_t* tbl_bf = (uint32_t*)wsc;
    uint32_t* wsb = (uint32_t*)(wsc + wsb_off);

    // pass 1: bf16-pack the hash tables
    const int npairs = (int)((size_t)kL * (size_t)kT / 2);
    convert_tables<<<(npairs + block - 1) / block, block, 0, stream>>>(
        (const float4*)hashmap, (uint2*)tbl_bf, npairs);

    // pass 2: build widened dense tables for levels 0-7
#define BUILD_OCT(R, L) build_oct<R, L><<<((R*R*R) + 255) / 256, 256, 0, stream>>>( \
        tbl_bf, (uint4*)(wsc + dense_off[L]))
    BUILD_OCT(16, 0); BUILD_OCT(20, 1); BUILD_OCT(25, 2);
    BUILD_OCT(32, 3); BUILD_OCT(40, 4);
#undef BUILD_OCT
    build_yz<50, 5><<<((51 * 50 * 50) + 255) / 256, 256, 0, stream>>>(
        tbl_bf, (uint4*)(wsc + dense_off[5]));
    build_dense2<64, 6><<<((65 * 65 * 64) + 255) / 256, 256, 0, stream>>>(
        tbl_bf, (uint2*)(wsc + dense_off[6]));
    build_dense1<80, 7><<<((81 * 81 * 81) + 255) / 256, 256, 0, stream>>>(
        tbl_bf, (uint32_t*)(wsc + dense_off[7]));

    // pass 3: mega level-major gather (r15 interleave reverted)
    Params16 prm;
    for (int l = 0; l < kL; ++l) {
        prm.res[l] = kRES[l];
        prm.fres[l] = (float)kRES[l];
        if (l < 5)       { prm.mode[l] = MODE_OCT;    prm.off[l] = dense_off[l]; }
        else if (l == 5) { prm.mode[l] = MODE_YZ;     prm.off[l] = dense_off[l]; }
        else if (l == 6) { prm.mode[l] = MODE_DENSE2; prm.off[l] = dense_off[l]; }
        else if (l == 7) { prm.mode[l] = MODE_DENSE1; prm.off[l] = dense_off[l]; }
        else             { prm.mode[l] = MODE_HASH;
                           prm.off[l] = (size_t)l * (size_t)kT * 4u; }
    }
    const int blocksPerLevel = ((P + 3) / 4 + block - 1) / block;
    hashgrid_levels<<<kL * blocksPerLevel, block, 0, stream>>>(
        x, wsc, wsb, P, blocksPerLevel, prm);

    // pass 4: transpose to [P,32]
    hashgrid_transpose<<<grid_p, block, 0, stream>>>(wsb, out4, P);
}

// Round 18
// 788.381 us; speedup vs baseline: 1.3708x; 1.0020x over previous
//
#include <hip/hip_runtime.h>
#include <cstdint>
#include <cstddef>

namespace {
constexpr int kL = 16;                    // levels
constexpr uint32_t kT = 1u << 19;         // hash table entries per level
constexpr uint32_t kTmask = kT - 1u;
constexpr uint32_t kP1 = 2654435761u;     // spatial hash primes
constexpr uint32_t kP2 = 805459861u;

constexpr int kRES[16] = {16, 20, 25, 32, 40, 50, 64, 80,
                          101, 128, 161, 203, 256, 322, 406, 512};

// level modes
constexpr int MODE_HASH = 0;   // random hash gather, 8x4B   (levels 9-15)
constexpr int MODE_DENSE1 = 1; // dense grid, 8x4B (z-pairs same line) (level 8)
constexpr int MODE_DENSE2 = 2; // dense z-pair, 4x8B         (level 7)
constexpr int MODE_YZ = 3;     // dense yz-face quad, 2x16B  (levels 5-6)
constexpr int MODE_OCT = 4;    // dense full octant, 2x16B   (levels 0-4)
}

__device__ __forceinline__ uint32_t hash3(uint32_t c0, uint32_t c1, uint32_t c2) {
    return (c0 ^ (c1 * kP1) ^ (c2 * kP2)) & kTmask;
}

__device__ __forceinline__ uint32_t f32_to_bf16_rne(float f) {
    const uint32_t u = __float_as_uint(f);
    return (u + 0x7fffu + ((u >> 16) & 1u)) >> 16;
}

// unpack packed bf16x2: low half = feature0, high = feature1
__device__ __forceinline__ float bfx(uint32_t u) { return __uint_as_float(u << 16); }
__device__ __forceinline__ float bfy(uint32_t u) { return __uint_as_float(u & 0xffff0000u); }

// ---------------------------------------------------------------------------
// Pre-pass 1: hashmap [L,T,F] f32 -> packed 2xbf16 per entry (4B).
// ---------------------------------------------------------------------------
__global__ __launch_bounds__(256) void convert_tables(
    const float4* __restrict__ hm4, uint2* __restrict__ tbl_bf, int npairs)
{
    const int i = blockIdx.x * 256 + threadIdx.x;
    if (i >= npairs) return;
    const float4 v = hm4[i];
    uint2 o;
    o.x = (f32_to_bf16_rne(v.y) << 16) | f32_to_bf16_rne(v.x);
    o.y = (f32_to_bf16_rne(v.w) << 16) | f32_to_bf16_rne(v.z);
    tbl_bf[i] = o;
}

// ---------------------------------------------------------------------------
// Pre-pass 2: widened dense tables (collision semantics preserved exactly:
// we copy hashed VALUES per corner; overlapping slots duplicate values).
// ---------------------------------------------------------------------------
// Octant: slot (c0,c1,c2), c* in [0,R-1], holds all 8 corners (32B).
template <int R, int LVL>
__global__ __launch_bounds__(256) void build_oct(
    const uint32_t* __restrict__ tbl_bf, uint4* __restrict__ oc)
{
    const int n = R * R * R;
    const int s = blockIdx.x * 256 + threadIdx.x;
    if (s >= n) return;
    const int c2 = s % R;
    const int t = s / R;
    const int c1 = t % R;
    const int c0 = t / R;
    const uint32_t* tbl = tbl_bf + (size_t)LVL * (size_t)kT;
    const uint32_t h0a = (uint32_t)c0, h0b = h0a + 1u;
    const uint32_t h1a = (uint32_t)c1 * kP1, h1b = h1a + kP1;
    const uint32_t h2a = (uint32_t)c2 * kP2, h2b = h2a + kP2;
    uint4 lo, hi;
    lo.x = tbl[(h0a ^ h1a ^ h2a) & kTmask];
    lo.y = tbl[(h0a ^ h1a ^ h2b) & kTmask];
    lo.z = tbl[(h0a ^ h1b ^ h2a) & kTmask];
    lo.w = tbl[(h0a ^ h1b ^ h2b) & kTmask];
    hi.x = tbl[(h0b ^ h1a ^ h2a) & kTmask];
    hi.y = tbl[(h0b ^ h1a ^ h2b) & kTmask];
    hi.z = tbl[(h0b ^ h1b ^ h2a) & kTmask];
    hi.w = tbl[(h0b ^ h1b ^ h2b) & kTmask];
    oc[2 * s + 0] = lo;
    oc[2 * s + 1] = hi;
}

// yz-face quad: slot (c0,c1,c2), c0 in [0,R], c1,c2 in [0,R-1]; holds the
// 4 corners (c0, c1+dy, c2+dz), dz fastest (16B).
template <int R, int LVL>
__global__ __launch_bounds__(256) void build_yz(
    const uint32_t* __restrict__ tbl_bf, uint4* __restrict__ fc)
{
    const int n = (R + 1) * R * R;
    const int s = blockIdx.x * 256 + threadIdx.x;
    if (s >= n) return;
    const int c2 = s % R;
    const int t = s / R;
    const int c1 = t % R;
    const int c0 = t / R;
    const uint32_t* tbl = tbl_bf + (size_t)LVL * (size_t)kT;
    const uint32_t h0 = (uint32_t)c0;
    const uint32_t h1a = (uint32_t)c1 * kP1, h1b = h1a + kP1;
    const uint32_t h2a = (uint32_t)c2 * kP2, h2b = h2a + kP2;
    uint4 f;
    f.x = tbl[(h0 ^ h1a ^ h2a) & kTmask];
    f.y = tbl[(h0 ^ h1a ^ h2b) & kTmask];
    f.z = tbl[(h0 ^ h1b ^ h2a) & kTmask];
    f.w = tbl[(h0 ^ h1b ^ h2b) & kTmask];
    fc[s] = f;
}

// z-pair: slot (c0,c1,c2), c0,c1 in [0,R], c2 in [0,R-1]; 8B.
template <int R, int LVL>
__global__ __launch_bounds__(256) void build_dense2(
    const uint32_t* __restrict__ tbl_bf, uint2* __restrict__ d2)
{
    const int n = (R + 1) * (R + 1) * R;
    const int s = blockIdx.x * 256 + threadIdx.x;
    if (s >= n) return;
    const int c2 = s % R;
    const int t = s / R;
    const int c1 = t % (R + 1);
    const int c0 = t / (R + 1);
    const uint32_t* tbl = tbl_bf + (size_t)LVL * (size_t)kT;
    uint2 o;
    o.x = tbl[hash3((uint32_t)c0, (uint32_t)c1, (uint32_t)c2)];
    o.y = tbl[hash3((uint32_t)c0, (uint32_t)c1, (uint32_t)(c2 + 1))];
    d2[s] = o;
}

// plain dense 4B (level 8; z-pair corners land in the same 64B line).
template <int R, int LVL>
__global__ __launch_bounds__(256) void build_dense1(
    const uint32_t* __restrict__ tbl_bf, uint32_t* __restrict__ d1)
{
    const int n = (R + 1) * (R + 1) * (R + 1);
    const int s = blockIdx.x * 256 + threadIdx.x;
    if (s >= n) return;
    const int c2 = s % (R + 1);
    const int t = s / (R + 1);
    const int c1 = t % (R + 1);
    const int c0 = t / (R + 1);
    const uint32_t* tbl = tbl_bf + (size_t)LVL * (size_t)kT;
    d1[s] = tbl[hash3((uint32_t)c0, (uint32_t)c1, (uint32_t)c2)];
}

// ---------------------------------------------------------------------------
struct Params16 {
    int mode[16];
    int res[16];
    float fres[16];
    unsigned long long off[16];   // byte offset of this level's table in ws
};

// ---------------------------------------------------------------------------
// MEGA level-major pass. 4 points/thread. Req/pt: OCT/YZ=2, DENSE2=4,
// DENSE1=8 (half L1-hit via z-pair lines), HASH=8. Empirical ceiling:
// ~0.45 gather-lines/cy/CU (r12-r16) — time tracks line-miss count.
// ---------------------------------------------------------------------------
__global__ __launch_bounds__(256, 4) void hashgrid_levels(
    const float* __restrict__ x,         // [P,3]
    const char* __restrict__ wsbase,     // ws base (tables live here)
    uint32_t* __restrict__ wsb,          // [kL][P] packed bf16x2 results
    int P, int blocksPerLevel, Params16 prm)
{
    const int l = blockIdx.x / blocksPerLevel;            // wave-uniform
    const int b = blockIdx.x - l * blocksPerLevel;
    const int t = b * 256 + threadIdx.x;
    const int p0 = 4 * t;
    if (p0 >= P) return;

    const int mode = prm.mode[l];
    const int R = prm.res[l];
    const float fres = prm.fres[l];
    const char* tblb = wsbase + prm.off[l];

    // load 4 points (3x float4, 16B-aligned since p0*12B % 16 == 0)
    float px[4], py[4], pz[4];
    if (p0 + 3 < P) {
        const float4* __restrict__ xp4 =
            reinterpret_cast<const float4*>(x + (size_t)p0 * 3);
        const float4 v0 = xp4[0], v1 = xp4[1], v2 = xp4[2];
        px[0] = v0.x; py[0] = v0.y; pz[0] = v0.z;
        px[1] = v0.w; py[1] = v1.x; pz[1] = v1.y;
        px[2] = v1.z; py[2] = v1.w; pz[2] = v2.x;
        px[3] = v2.y; py[3] = v2.z; pz[3] = v2.w;
    } else {
#pragma unroll
        for (int q = 0; q < 4; ++q) {
            const int pc = (p0 + q < P) ? (p0 + q) : (P - 1);
            px[q] = x[(size_t)pc * 3 + 0];
            py[q] = x[(size_t)pc * 3 + 1];
            pz[q] = x[(size_t)pc * 3 + 2];
        }
    }

    // geometry (fp32 ops match the reference exactly)
    int i0[4], i1[4], i2[4];
    float fx[4], fy[4], fz[4];
#pragma unroll
    for (int q = 0; q < 4; ++q) {
        const float xs0 = px[q] * fres, xs1 = py[q] * fres, xs2 = pz[q] * fres;
        const float fl0 = floorf(xs0), fl1 = floorf(xs1), fl2 = floorf(xs2);
        fx[q] = xs0 - fl0; fy[q] = xs1 - fl1; fz[q] = xs2 - fl2;
        i0[q] = (int)fl0; i1[q] = (int)fl1; i2[q] = (int)fl2;
    }

    float r0[4], r1[4];

    if (mode == MODE_OCT) {
        // slot (x,y,z) -> 8 corners in 32B: 2x uint4, same 32B chunk
        const uint4* __restrict__ oc = reinterpret_cast<const uint4*>(tblb);
        uint4 lo[4], hi[4];
#pragma unroll
        for (int q = 0; q < 4; ++q) {
            const int s = (i0[q] * R + i1[q]) * R + i2[q];
            lo[q] = oc[2 * s + 0];
            hi[q] = oc[2 * s + 1];
        }
#pragma unroll
        for (int q = 0; q < 4; ++q) {
            const float wx0 = 1.0f - fx[q], wx1 = fx[q];
            const float wy0 = 1.0f - fy[q], wy1 = fy[q];
            const float wz0 = 1.0f - fz[q], wz1 = fz[q];
            float w[8];
            w[0] = wx0 * wy0 * wz0; w[1] = wx0 * wy0 * wz1;
            w[2] = wx0 * wy1 * wz0; w[3] = wx0 * wy1 * wz1;
            w[4] = wx1 * wy0 * wz0; w[5] = wx1 * wy0 * wz1;
            w[6] = wx1 * wy1 * wz0; w[7] = wx1 * wy1 * wz1;
            float a0 = 0.0f, a1 = 0.0f;
            a0 = fmaf(w[0], bfx(lo[q].x), a0); a1 = fmaf(w[0], bfy(lo[q].x), a1);
            a0 = fmaf(w[1], bfx(lo[q].y), a0); a1 = fmaf(w[1], bfy(lo[q].y), a1);
            a0 = fmaf(w[2], bfx(lo[q].z), a0); a1 = fmaf(w[2], bfy(lo[q].z), a1);
            a0 = fmaf(w[3], bfx(lo[q].w), a0); a1 = fmaf(w[3], bfy(lo[q].w), a1);
            a0 = fmaf(w[4], bfx(hi[q].x), a0); a1 = fmaf(w[4], bfy(hi[q].x), a1);
            a0 = fmaf(w[5], bfx(hi[q].y), a0); a1 = fmaf(w[5], bfy(hi[q].y), a1);
            a0 = fmaf(w[6], bfx(hi[q].z), a0); a1 = fmaf(w[6], bfy(hi[q].z), a1);
            a0 = fmaf(w[7], bfx(hi[q].w), a0); a1 = fmaf(w[7], bfy(hi[q].w), a1);
            r0[q] = a0; r1[q] = a1;
        }
    } else if (mode == MODE_YZ) {
        // slot (x,y,z) -> 4 corners (x, y+dy, z+dz) in 16B; read x and x+1
        const uint4* __restrict__ fc = reinterpret_cast<const uint4*>(tblb);
        const int sX = R * R;
        uint4 f0[4], f1[4];
#pragma unroll
        for (int q = 0; q < 4; ++q) {
            const int s = (i0[q] * R + i1[q]) * R + i2[q];
            f0[q] = fc[s];
            f1[q] = fc[s + sX];
        }
#pragma unroll
        for (int q = 0; q < 4; ++q) {
            const float wx0 = 1.0f - fx[q], wx1 = fx[q];
            const float wy0 = 1.0f - fy[q], wy1 = fy[q];
            const float wz0 = 1.0f - fz[q], wz1 = fz[q];
            float w[8];
            w[0] = wx0 * wy0 * wz0; w[1] = wx0 * wy0 * wz1;
            w[2] = wx0 * wy1 * wz0; w[3] = wx0 * wy1 * wz1;
            w[4] = wx1 * wy0 * wz0; w[5] = wx1 * wy0 * wz1;
            w[6] = wx1 * wy1 * wz0; w[7] = wx1 * wy1 * wz1;
            float a0 = 0.0f, a1 = 0.0f;
            a0 = fmaf(w[0], bfx(f0[q].x), a0); a1 = fmaf(w[0], bfy(f0[q].x), a1);
            a0 = fmaf(w[1], bfx(f0[q].y), a0); a1 = fmaf(w[1], bfy(f0[q].y), a1);
            a0 = fmaf(w[2], bfx(f0[q].z), a0); a1 = fmaf(w[2], bfy(f0[q].z), a1);
            a0 = fmaf(w[3], bfx(f0[q].w), a0); a1 = fmaf(w[3], bfy(f0[q].w), a1);
            a0 = fmaf(w[4], bfx(f1[q].x), a0); a1 = fmaf(w[4], bfy(f1[q].x), a1);
            a0 = fmaf(w[5], bfx(f1[q].y), a0); a1 = fmaf(w[5], bfy(f1[q].y), a1);
            a0 = fmaf(w[6], bfx(f1[q].z), a0); a1 = fmaf(w[6], bfy(f1[q].z), a1);
            a0 = fmaf(w[7], bfx(f1[q].w), a0); a1 = fmaf(w[7], bfy(f1[q].w), a1);
            r0[q] = a0; r1[q] = a1;
        }
    } else if (mode == MODE_DENSE2) {
        const uint2* __restrict__ d2 = reinterpret_cast<const uint2*>(tblb);
        const int sB = R, sA = R * (R + 1);
        uint2 u[4][4];
#pragma unroll
        for (int q = 0; q < 4; ++q) {
            const int base = (i0[q] * (R + 1) + i1[q]) * R + i2[q];
            u[q][0] = d2[base];
            u[q][1] = d2[base + sB];
            u[q][2] = d2[base + sA];
            u[q][3] = d2[base + sA + sB];
        }
#pragma unroll
        for (int q = 0; q < 4; ++q) {
            const float wx0 = 1.0f - fx[q], wx1 = fx[q];
            const float wy0 = 1.0f - fy[q], wy1 = fy[q];
            const float wz0 = 1.0f - fz[q], wz1 = fz[q];
            const float w00 = wx0 * wy0, w01 = wx0 * wy1;
            const float w10 = wx1 * wy0, w11 = wx1 * wy1;
            float a0 = 0.0f, a1 = 0.0f;
            a0 = fmaf(w00 * wz0, bfx(u[q][0].x), a0); a1 = fmaf(w00 * wz0, bfy(u[q][0].x), a1);
            a0 = fmaf(w00 * wz1, bfx(u[q][0].y), a0); a1 = fmaf(w00 * wz1, bfy(u[q][0].y), a1);
            a0 = fmaf(w01 * wz0, bfx(u[q][1].x), a0); a1 = fmaf(w01 * wz0, bfy(u[q][1].x), a1);
            a0 = fmaf(w01 * wz1, bfx(u[q][1].y), a0); a1 = fmaf(w01 * wz1, bfy(u[q][1].y), a1);
            a0 = fmaf(w10 * wz0, bfx(u[q][2].x), a0); a1 = fmaf(w10 * wz0, bfy(u[q][2].x), a1);
            a0 = fmaf(w10 * wz1, bfx(u[q][2].y), a0); a1 = fmaf(w10 * wz1, bfy(u[q][2].y), a1);
            a0 = fmaf(w11 * wz0, bfx(u[q][3].x), a0); a1 = fmaf(w11 * wz0, bfy(u[q][3].x), a1);
            a0 = fmaf(w11 * wz1, bfx(u[q][3].y), a0); a1 = fmaf(w11 * wz1, bfy(u[q][3].y), a1);
            r0[q] = a0; r1[q] = a1;
        }
    } else {
        // MODE_DENSE1 / MODE_HASH: 8x 4B gathers per point
        const uint32_t* __restrict__ tbl = reinterpret_cast<const uint32_t*>(tblb);
        uint32_t idx[4][8];
        if (mode == MODE_DENSE1) {
            const int sB = R + 1, sA = (R + 1) * (R + 1);
#pragma unroll
            for (int q = 0; q < 4; ++q) {
                const int base = (i0[q] * (R + 1) + i1[q]) * (R + 1) + i2[q];
                idx[q][0] = base;           idx[q][1] = base + 1;
                idx[q][2] = base + sB;      idx[q][3] = base + sB + 1;
                idx[q][4] = base + sA;      idx[q][5] = base + sA + 1;
                idx[q][6] = base + sA + sB; idx[q][7] = base + sA + sB + 1;
            }
        } else {
#pragma unroll
            for (int q = 0; q < 4; ++q) {
                const uint32_t h0a = (uint32_t)i0[q], h0b = h0a + 1u;
                const uint32_t h1a = (uint32_t)i1[q] * kP1, h1b = h1a + kP1;
                const uint32_t h2a = (uint32_t)i2[q] * kP2, h2b = h2a + kP2;
                idx[q][0] = (h0a ^ h1a ^ h2a) & kTmask;
                idx[q][1] = (h0a ^ h1a ^ h2b) & kTmask;
                idx[q][2] = (h0a ^ h1b ^ h2a) & kTmask;
                idx[q][3] = (h0a ^ h1b ^ h2b) & kTmask;
                idx[q][4] = (h0b ^ h1a ^ h2a) & kTmask;
                idx[q][5] = (h0b ^ h1a ^ h2b) & kTmask;
                idx[q][6] = (h0b ^ h1b ^ h2a) & kTmask;
                idx[q][7] = (h0b ^ h1b ^ h2b) & kTmask;
            }
        }
        uint32_t u[4][8];
#pragma unroll
        for (int q = 0; q < 4; ++q) {
#pragma unroll
            for (int c = 0; c < 8; ++c) u[q][c] = tbl[idx[q][c]];
        }
#pragma unroll
        for (int q = 0; q < 4; ++q) {
            const float wx0 = 1.0f - fx[q], wx1 = fx[q];
            const float wy0 = 1.0f - fy[q], wy1 = fy[q];
            const float wz0 = 1.0f - fz[q], wz1 = fz[q];
            float w[8];
            w[0] = wx0 * wy0 * wz0; w[1] = wx0 * wy0 * wz1;
            w[2] = wx0 * wy1 * wz0; w[3] = wx0 * wy1 * wz1;
            w[4] = wx1 * wy0 * wz0; w[5] = wx1 * wy0 * wz1;
            w[6] = wx1 * wy1 * wz0; w[7] = wx1 * wy1 * wz1;
            float a0 = 0.0f, a1 = 0.0f;
#pragma unroll
            for (int c = 0; c < 8; ++c) {
                a0 = fmaf(w[c], bfx(u[q][c]), a0);
                a1 = fmaf(w[c], bfy(u[q][c]), a1);
            }
            r0[q] = a0; r1[q] = a1;
        }
    }

    uint32_t pk[4];
#pragma unroll
    for (int q = 0; q < 4; ++q)
        pk[q] = (f32_to_bf16_rne(r1[q]) << 16) | f32_to_bf16_rne(r0[q]);

    uint32_t* dst = wsb + (size_t)l * (size_t)P + (size_t)p0;
    if (p0 + 3 < P) {
        *reinterpret_cast<uint4*>(dst) = make_uint4(pk[0], pk[1], pk[2], pk[3]);
    } else {
#pragma unroll
        for (int q = 0; q < 4; ++q)
            if (p0 + q < P) dst[q] = pk[q];
    }
}

// ---------------------------------------------------------------------------
// wsb[l][p] bf16x2 -> out[p][32] f32, LDS-staged, both sides coalesced.
// ---------------------------------------------------------------------------
__global__ __launch_bounds__(256) void hashgrid_transpose(
    const uint32_t* __restrict__ wsb, float4* __restrict__ out4, int P)
{
    __shared__ uint32_t lds[256 * 17];
    const int tid = threadIdx.x;
    const int base = blockIdx.x * 256;

#pragma unroll
    for (int l = 0; l < kL; ++l) {
        const int p = base + tid;
        const uint32_t v = (p < P) ? wsb[(size_t)l * (size_t)P + (size_t)p] : 0u;
        lds[tid * 17 + l] = v;
    }
    __syncthreads();

    const int nvec = min(P - base, 256) * 8;
#pragma unroll
    for (int j = 0; j < 8; ++j) {
        const int tvec = j * 256 + tid;
        if (tvec < nvec) {
            const int pl = tvec >> 3;
            const int m = tvec & 7;
            const uint32_t ua = lds[pl * 17 + 2 * m];
            const uint32_t ub = lds[pl * 17 + 2 * m + 1];
            out4[(size_t)base * 8 + (size_t)tvec] =
                make_float4(bfx(ua), bfy(ua), bfx(ub), bfy(ub));
        }
    }
}

// ---------------------------------------------------------------------------
// Fallback (monolithic fp32): only if ws too small.
// ---------------------------------------------------------------------------
__global__ __launch_bounds__(256) void hashgrid_fwd_mono(
    const float* __restrict__ x, const float* __restrict__ hashmap,
    float4* __restrict__ out4, int P)
{
    const int p = blockIdx.x * 256 + threadIdx.x;
    if (p >= P) return;
    const float px = x[p * 3 + 0], py = x[p * 3 + 1], pz = x[p * 3 + 2];
    float acc[32];
#pragma unroll
    for (int l = 0; l < kL; ++l) {
        const float fres = (float)kRES[l];
        const float xs0 = px * fres, xs1 = py * fres, xs2 = pz * fres;
        const float fl0 = floorf(xs0), fl1 = floorf(xs1), fl2 = floorf(xs2);
        const float fx = xs0 - fl0, fy = xs1 - fl1, fz = xs2 - fl2;
        const uint32_t i0 = (uint32_t)(int)fl0, i1 = (uint32_t)(int)fl1, i2 = (uint32_t)(int)fl2;
        const uint32_t h0a = i0, h0b = i0 + 1u;
        const uint32_t h1a = i1 * kP1, h1b = (i1 + 1u) * kP1;
        const uint32_t h2a = i2 * kP2, h2b = (i2 + 1u) * kP2;
        uint32_t idx[8];
        idx[0] = (h0a ^ h1a ^ h2a) & kTmask; idx[1] = (h0a ^ h1a ^ h2b) & kTmask;
        idx[2] = (h0a ^ h1b ^ h2a) & kTmask; idx[3] = (h0a ^ h1b ^ h2b) & kTmask;
        idx[4] = (h0b ^ h1a ^ h2a) & kTmask; idx[5] = (h0b ^ h1a ^ h2b) & kTmask;
        idx[6] = (h0b ^ h1b ^ h2a) & kTmask; idx[7] = (h0b ^ h1b ^ h2b) & kTmask;
        const float2* tbl = reinterpret_cast<const float2*>(hashmap) + (size_t)l * kT;
        float2 f[8];
#pragma unroll
        for (int c = 0; c < 8; ++c) f[c] = tbl[idx[c]];
        const float wx0 = 1.0f - fx, wx1 = fx;
        const float wy0 = 1.0f - fy, wy1 = fy;
        const float wz0 = 1.0f - fz, wz1 = fz;
        float w[8];
        w[0] = wx0 * wy0 * wz0; w[1] = wx0 * wy0 * wz1;
        w[2] = wx0 * wy1 * wz0; w[3] = wx0 * wy1 * wz1;
        w[4] = wx1 * wy0 * wz0; w[5] = wx1 * wy0 * wz1;
        w[6] = wx1 * wy1 * wz0; w[7] = wx1 * wy1 * wz1;
        float a0 = 0.0f, a1 = 0.0f;
#pragma unroll
        for (int c = 0; c < 8; ++c) {
            a0 = fmaf(w[c], f[c].x, a0);
            a1 = fmaf(w[c], f[c].y, a1);
        }
        acc[2 * l + 0] = a0; acc[2 * l + 1] = a1;
    }
    float4* dst = out4 + (size_t)p * 8;
#pragma unroll
    for (int j = 0; j < 8; ++j)
        dst[j] = make_float4(acc[4 * j], acc[4 * j + 1], acc[4 * j + 2], acc[4 * j + 3]);
}

extern "C" void kernel_launch(void* const* d_in, const int* in_sizes, int n_in,
                              void* d_out, int out_size, void* d_ws, size_t ws_size,
                              hipStream_t stream) {
    const float* x = (const float*)d_in[0];
    const float* hashmap = (const float*)d_in[1];
    float4* out4 = (float4*)d_out;

    const int P = in_sizes[0] / 3;
    const int block = 256;
    const int grid_p = (P + block - 1) / block;

    // ws layout: [0,32MB) bf16 hash tables | widened dense tables (L0-8) | wsb
    const size_t tbl_bytes = (size_t)kL * (size_t)kT * 4u;               // 32 MB
    size_t dense_off[9];
    size_t cur = tbl_bytes;
    for (int l = 0; l < 9; ++l) {
        const size_t R = (size_t)kRES[l];
        size_t bytes;
        if (l < 5)       bytes = R * R * R * 32;                  // octant
        else if (l <= 6) bytes = (R + 1) * R * R * 16;            // yz-face
        else if (l == 7) bytes = (R + 1) * (R + 1) * R * 8;       // z-pair
        else             bytes = (R + 1) * (R + 1) * (R + 1) * 4; // dense1
        cur = (cur + 255) & ~(size_t)255;
        dense_off[l] = cur;
        cur += bytes;
    }
    cur = (cur + 255) & ~(size_t)255;
    const size_t wsb_off = cur;
    const size_t need = wsb_off + (size_t)kL * (size_t)P * 4u;
    if (ws_size < need) {
        hashgrid_fwd_mono<<<grid_p, block, 0, stream>>>(x, hashmap, out4, P);
        return;
    }

    char* wsc = (char*)d_ws;
    uint32_t* tbl_bf = (uint32_t*)wsc;
    uint32_t* wsb = (uint32_t*)(wsc + wsb_off);

    // pass 1: bf16-pack the hash tables
    const int npairs = (int)((size_t)kL * (size_t)kT / 2);
    convert_tables<<<(npairs + block - 1) / block, block, 0, stream>>>(
        (const float4*)hashmap, (uint2*)tbl_bf, npairs);

    // pass 2: build widened dense tables for levels 0-8
#define BUILD_OCT(R, L) build_oct<R, L><<<((R*R*R) + 255) / 256, 256, 0, stream>>>( \
        tbl_bf, (uint4*)(wsc + dense_off[L]))
    BUILD_OCT(16, 0); BUILD_OCT(20, 1); BUILD_OCT(25, 2);
    BUILD_OCT(32, 3); BUILD_OCT(40, 4);
#undef BUILD_OCT
    build_yz<50, 5><<<((51 * 50 * 50) + 255) / 256, 256, 0, stream>>>(
        tbl_bf, (uint4*)(wsc + dense_off[5]));
    build_yz<64, 6><<<((65 * 64 * 64) + 255) / 256, 256, 0, stream>>>(
        tbl_bf, (uint4*)(wsc + dense_off[6]));
    build_dense2<80, 7><<<((81 * 81 * 80) + 255) / 256, 256, 0, stream>>>(
        tbl_bf, (uint2*)(wsc + dense_off[7]));
    build_dense1<101, 8><<<((102 * 102 * 102) + 255) / 256, 256, 0, stream>>>(
        tbl_bf, (uint32_t*)(wsc + dense_off[8]));

    // pass 3: mega level-major gather
    Params16 prm;
    for (int l = 0; l < kL; ++l) {
        prm.res[l] = kRES[l];
        prm.fres[l] = (float)kRES[l];
        if (l < 5)       { prm.mode[l] = MODE_OCT;    prm.off[l] = dense_off[l]; }
        else if (l <= 6) { prm.mode[l] = MODE_YZ;     prm.off[l] = dense_off[l]; }
        else if (l == 7) { prm.mode[l] = MODE_DENSE2; prm.off[l] = dense_off[l]; }
        else if (l == 8) { prm.mode[l] = MODE_DENSE1; prm.off[l] = dense_off[l]; }
        else             { prm.mode[l] = MODE_HASH;
                           prm.off[l] = (size_t)l * (size_t)kT * 4u; }
    }
    const int blocksPerLevel = ((P + 3) / 4 + block - 1) / block;
    hashgrid_levels<<<kL * blocksPerLevel, block, 0, stream>>>(
        x, wsc, wsb, P, blocksPerLevel, prm);

    // pass 4: transpose to [P,32]
    hashgrid_transpose<<<grid_p, block, 0, stream>>>(wsb, out4, P);
}